// Round 10
// baseline (88.803 us; speedup 1.0000x reference)
//
#include <hip/hip_runtime.h>
#include <math.h>

#define HID 50
#define NPTS 8192
#define NPARA 5000
#define NLAYERS 4
#define NBLK 256           // blocks; each handles 2 independent 16-point tiles

typedef float f32x4 __attribute__((ext_vector_type(4)));
typedef short short8 __attribute__((ext_vector_type(8)));

union U4S8 { uint4 u; short8 s; };

// ---- workspace layout (bytes) ----
#define WS_PART 0          // 512 tile-sets * 6 doubles = 24576
#define WS_FRAG 32768      // 32 frag-units * 2(hi/lo) * 64 lanes * 16B = 65536
#define WS_WIN  98304      // W_in padded 3*64 f32
#define WS_BIN  99072      // b_in padded 64 f32
#define WS_BH   99328      // b_hid padded 4*64 f32
#define WS_WOUT 100352     // W_out padded 64*2 f32
#define WS_NEED 100864

// packed state: S[comp][k][p] as u32 (bf16 hi | lo<<16), k-stride 21 words
// (all read/write patterns <=2-way bank aliasing = free; 0 conflicts measured)
#define S_STRIDE 21
#define S_COMP   (64*S_STRIDE)      // 1344 u32 per component
#define S_WORDS  (6*S_COMP)         // 8064 u32 = 32256 B per tile
// two tiles: 2*S_WORDS = 16128 u32 = 64512 B  (< 64 KB static LDS cap)

#define SEL_HI 0x05040100u
#define SEL_LO 0x07060302u

__device__ __forceinline__ float fast_tanh(float x) {
    const float ax = __builtin_fabsf(x);
    const float e  = __expf(2.0f * ax);
    const float r  = __builtin_amdgcn_rcpf(e + 1.0f);
    const float t  = fmaf(-2.0f, r, 1.0f);
    return __builtin_copysignf(t, x);
}

// split fp32 ~= hi + lo (bf16 each), |err| ~ 2^-17 |x|
__device__ __forceinline__ void split_bf16(float x, unsigned &hi, unsigned &lo) {
    const unsigned u = __float_as_uint(x);
    const unsigned h = u & 0xFFFF0000u;
    const float rem  = x - __uint_as_float(h);
    const unsigned r = __float_as_uint(rem);
    hi = h >> 16;
    lo = (r + 0x7FFFu + ((r >> 16) & 1u)) >> 16;
}

__device__ __forceinline__ unsigned pack_split(float x) {
    unsigned hi, lo;
    split_bf16(x, hi, lo);
    return hi | (lo << 16);
}

__device__ __forceinline__ float unpack_sum(unsigned w) {
    return __uint_as_float(w << 16) + __uint_as_float(w & 0xFFFF0000u);
}

__device__ __forceinline__ uint4 pack8(const unsigned v[8]) {
    return make_uint4(v[0] | (v[1] << 16), v[2] | (v[3] << 16),
                      v[4] | (v[5] << 16), v[6] | (v[7] << 16));
}

// ---- prep: split weights into bf16 hi/lo B-fragments + pad arrays ----
// B-frag for (l,c,t): lane(q=lane>>4, n=lane&15) holds B[k=c*32+q*8+jj][t*16+n]
__global__ __launch_bounds__(256) void prep_kernel(
    const float* __restrict__ W_in, const float* __restrict__ b_in,
    const float* __restrict__ W_hid, const float* __restrict__ b_hid,
    const float* __restrict__ W_out, char* __restrict__ wsbase)
{
    const int gid = blockIdx.x * 256 + threadIdx.x;
    if (gid < 2048) {
        const int fid = gid >> 6, lane = gid & 63;
        const int l = fid >> 3, c = (fid >> 2) & 1, t = fid & 3;
        const int q = lane >> 4, n = lane & 15;
        const int gn = t*16 + n;
        unsigned hi[8], lo[8];
        #pragma unroll
        for (int jj = 0; jj < 8; ++jj) {
            const int k = c*32 + q*8 + jj;
            const float w = (k < HID && gn < HID) ? W_hid[(l*HID + k)*HID + gn] : 0.f;
            split_bf16(w, hi[jj], lo[jj]);
        }
        uint4* frag = (uint4*)(wsbase + WS_FRAG);
        frag[(fid*2 + 0)*64 + lane] = pack8(hi);
        frag[(fid*2 + 1)*64 + lane] = pack8(lo);
    } else if (gid < 2240) {
        const int i = gid - 2048, d = i >> 6, j = i & 63;
        ((float*)(wsbase + WS_WIN))[i] = (j < HID) ? W_in[d*HID + j] : 0.f;
    } else if (gid < 2304) {
        const int j = gid - 2240;
        ((float*)(wsbase + WS_BIN))[j] = (j < HID) ? b_in[j] : 0.f;
    } else if (gid < 2560) {
        const int i = gid - 2304, l = i >> 6, j = i & 63;
        ((float*)(wsbase + WS_BH))[i] = (j < HID) ? b_hid[l*HID + j] : 0.f;
    } else if (gid < 2688) {
        const int i = gid - 2560, j = i >> 1, s = i & 1;
        ((float*)(wsbase + WS_WOUT))[i] = (j < HID) ? W_out[j*2 + s] : 0.f;
    }
}

// ---- main: 8 waves/block = 2 point-tiles x 4 j-tile waves; 32 points/block ----
__global__ __launch_bounds__(512, 2) void point_mfma_kernel(
    const float* __restrict__ x,
    const float* __restrict__ b_out,
    const char* __restrict__ wsbase,
    double* __restrict__ part)
{
    __shared__ unsigned S[2 * S_WORDS];

    const int tid  = threadIdx.x;
    const int wave = tid >> 6;
    const int lane = tid & 63;
    const int g    = wave & 1;        // point-tile group
    const int jt   = wave >> 1;       // j-tile 0..3
    const int q = lane >> 4, L = lane & 15;
    unsigned* __restrict__ Sg = &S[g * S_WORDS];
    // xd overlay: dead S space reused for the cross-wave output reduction
    float* __restrict__ xdg = (float*)&S[g * S_WORDS];

    const float* Winp = (const float*)(wsbase + WS_WIN);
    const float* binp = (const float*)(wsbase + WS_BIN);
    const float* bhp  = (const float*)(wsbase + WS_BH);
    const float* wop  = (const float*)(wsbase + WS_WOUT);
    const uint4* frag = (const uint4*)(wsbase + WS_FRAG);

    // ---- input layer: lane (q,L) seeds j = 16*jt+4q+jj (jj<4) for point p=L ----
    const int pid = (blockIdx.x * 2 + g) * 16 + L;
    const float x0 = x[3*pid+0], x1 = x[3*pid+1], x2 = x[3*pid+2];
    #pragma unroll
    for (int jj = 0; jj < 4; ++jj) {
        const int j = 16*jt + 4*q + jj;
        const float w0 = Winp[j], w1 = Winp[64 + j], w2 = Winp[128 + j];
        const float z  = fmaf(x0, w0, fmaf(x1, w1, fmaf(x2, w2, binp[j])));
        const float h  = fast_tanh(z);
        const float s  = 1.f - h*h;
        const float gg = -2.f*h*s;
        const int base = j*S_STRIDE + L;
        Sg[0*S_COMP + base] = pack_split(h);
        Sg[1*S_COMP + base] = pack_split(s*w0);
        Sg[2*S_COMP + base] = pack_split(s*w1);
        Sg[3*S_COMP + base] = pack_split(s*w2);
        Sg[4*S_COMP + base] = pack_split(gg*w0*w0);
        Sg[5*S_COMP + base] = pack_split(gg*w1*w1);
    }
    __syncthreads();

    // ---- hidden layers ----
    #pragma unroll 1
    for (int l = 0; l < NLAYERS; ++l) {
        f32x4 acc[6];
        #pragma unroll
        for (int comp = 0; comp < 6; ++comp) acc[comp] = (f32x4){0.f,0.f,0.f,0.f};

        #pragma unroll
        for (int c = 0; c < 2; ++c) {
            U4S8 bh, bl;
            {
                const int fi = (l*2 + c)*4 + jt;
                bh.u = frag[(fi*2 + 0)*64 + lane];
                bl.u = frag[(fi*2 + 1)*64 + lane];
            }
            #pragma unroll
            for (int comp = 0; comp < 6; ++comp) {
                const int base = comp*S_COMP + (c*32 + q*8)*S_STRIDE + L;
                unsigned w[8];
                #pragma unroll
                for (int jj = 0; jj < 8; ++jj) w[jj] = Sg[base + jj*S_STRIDE];
                U4S8 ah, al;
                ah.u = make_uint4(
                    __builtin_amdgcn_perm(w[1], w[0], SEL_HI),
                    __builtin_amdgcn_perm(w[3], w[2], SEL_HI),
                    __builtin_amdgcn_perm(w[5], w[4], SEL_HI),
                    __builtin_amdgcn_perm(w[7], w[6], SEL_HI));
                al.u = make_uint4(
                    __builtin_amdgcn_perm(w[1], w[0], SEL_LO),
                    __builtin_amdgcn_perm(w[3], w[2], SEL_LO),
                    __builtin_amdgcn_perm(w[5], w[4], SEL_LO),
                    __builtin_amdgcn_perm(w[7], w[6], SEL_LO));
                acc[comp] = __builtin_amdgcn_mfma_f32_16x16x32_bf16(ah.s, bh.s, acc[comp], 0, 0, 0);
                acc[comp] = __builtin_amdgcn_mfma_f32_16x16x32_bf16(ah.s, bl.s, acc[comp], 0, 0, 0);
                acc[comp] = __builtin_amdgcn_mfma_f32_16x16x32_bf16(al.s, bh.s, acc[comp], 0, 0, 0);
            }
        }
        __syncthreads();   // all reads drained before epilogue overwrites S

        // epilogue: C/D col(j)=lane&15, row(p)=q*4+r -> write S[comp][j][p]
        {
            const int j = jt*16 + L;
            const float bias = bhp[l*64 + j];
            #pragma unroll
            for (int r = 0; r < 4; ++r) {
                const int p = 4*q + r;
                const float za  = acc[0][r] + bias;
                const float zx  = acc[1][r];
                const float zy  = acc[2][r];
                const float zt  = acc[3][r];
                const float zxx = acc[4][r];
                const float zyy = acc[5][r];
                const float h = fast_tanh(za);
                const float s = 1.f - h*h;
                const float gg = -2.f*h*s;
                const int base = j*S_STRIDE + p;
                Sg[0*S_COMP + base] = pack_split(h);
                Sg[1*S_COMP + base] = pack_split(s*zx);
                Sg[2*S_COMP + base] = pack_split(s*zy);
                Sg[3*S_COMP + base] = pack_split(s*zt);
                Sg[4*S_COMP + base] = pack_split(fmaf(gg*zx, zx, s*zxx));
                Sg[5*S_COMP + base] = pack_split(fmaf(gg*zy, zy, s*zyy));
            }
        }
        __syncthreads();
    }

    // ---- output layer: lane (q,L) sums j = 16*jt+4q+jj (jj<4) for point L ----
    float du=0.f, dv=0.f, dut=0.f, dvt=0.f, duxx=0.f, dvxx=0.f, duyy=0.f, dvyy=0.f;
    #pragma unroll
    for (int jj = 0; jj < 4; ++jj) {
        const int j = 16*jt + 4*q + jj;
        const int base = j*S_STRIDE + L;
        const float sh  = unpack_sum(Sg[0*S_COMP + base]);
        const float st_ = unpack_sum(Sg[3*S_COMP + base]);
        const float sxx = unpack_sum(Sg[4*S_COMP + base]);
        const float syy = unpack_sum(Sg[5*S_COMP + base]);
        const float w0 = wop[j*2 + 0], w1 = wop[j*2 + 1];
        du   = fmaf(sh,  w0, du);   dv   = fmaf(sh,  w1, dv);
        dut  = fmaf(st_, w0, dut);  dvt  = fmaf(st_, w1, dvt);
        duxx = fmaf(sxx, w0, duxx); dvxx = fmaf(sxx, w1, dvxx);
        duyy = fmaf(syy, w0, duyy); dvyy = fmaf(syy, w1, dvyy);
    }
    #pragma unroll
    for (int off = 16; off <= 32; off <<= 1) {   // reduce over q
        du   += __shfl_xor(du,   off); dv   += __shfl_xor(dv,   off);
        dut  += __shfl_xor(dut,  off); dvt  += __shfl_xor(dvt,  off);
        duxx += __shfl_xor(duxx, off); dvxx += __shfl_xor(dvxx, off);
        duyy += __shfl_xor(duyy, off); dvyy += __shfl_xor(dvyy, off);
    }
    __syncthreads();   // output-stage S reads done (both groups) -> xd overlay safe
    if (jt >= 1 && lane < 16) {
        float* d = &xdg[((jt-1)*16 + lane) * 8];
        d[0]=du; d[1]=dv; d[2]=dut; d[3]=dvt;
        d[4]=duxx; d[5]=dvxx; d[6]=duyy; d[7]=dvyy;
    }
    __syncthreads();
    if (jt == 0) {
        #pragma unroll
        for (int wv = 0; wv < 3; ++wv) {
            const float* d = &xdg[(wv*16 + L) * 8];
            du += d[0]; dv += d[1]; dut += d[2]; dvt += d[3];
            duxx += d[4]; dvxx += d[5]; duyy += d[6]; dvyy += d[7];
        }
        const float u = du + b_out[0];
        const float v = dv + b_out[1];
        const float Q = u*u + v*v;
        const float g1 = dvt - 0.5f*duxx - 0.5f*dvyy - Q*u + v;   // base1
        const float g2 = dut + 0.5f*dvxx - 0.5f*duyy + Q*v + u;   // base2
        const float h1 = 0.5f*duyy, h2 = 0.5f*dvyy;
        const float k1 = Q*v,       k2 = Q*u;

        const double m = (lane < 16) ? 1.0 : 0.0;   // one contribution per point
        double a0 = m * ((double)g1*(double)g1 + (double)g2*(double)g2);
        double a1 = m * ((double)h1*(double)h1 + (double)h2*(double)h2);
        double a2 = m * ((double)k1*(double)k1 + (double)k2*(double)k2);
        double a3 = m * ((double)g2*(double)h2 - (double)g1*(double)h1);
        double a4 = m * ((double)g1*(double)k1 + (double)g2*(double)k2);
        double a5 = m * ((double)h1*(double)k1 - (double)h2*(double)k2);
        #pragma unroll
        for (int off = 1; off <= 32; off <<= 1) {
            a0 += __shfl_xor(a0, off); a1 += __shfl_xor(a1, off);
            a2 += __shfl_xor(a2, off); a3 += __shfl_xor(a3, off);
            a4 += __shfl_xor(a4, off); a5 += __shfl_xor(a5, off);
        }
        if (lane == 0) {
            double* o = &part[(blockIdx.x * 2 + g) * 6];
            o[0] = a0; o[1] = a1; o[2] = a2; o[3] = a3; o[4] = a4; o[5] = a5;
        }
    }
}

// =================== fallback (proven R4 readlane kernel) ===================
#define BLOCK_F 1024
#define WPB_F   16
#define GRID_F  512
#define SWIN_SZ (3*HID + 16)
#define SBIN_SZ (HID + 16)
#define SWH_SZ  (NLAYERS*HID*HID + 16)
#define SBH_SZ  (NLAYERS*HID + 16)
#define SWO_SZ  (2*64)

__device__ __forceinline__ float readlane_f(float v, int k) {
    return __int_as_float(__builtin_amdgcn_readlane(__float_as_int(v), k));
}

__global__ __launch_bounds__(BLOCK_F, 8) void point_fallback_kernel(
    const float* __restrict__ x,
    const float* __restrict__ W_in, const float* __restrict__ b_in,
    const float* __restrict__ W_hid, const float* __restrict__ b_hid,
    const float* __restrict__ W_out, const float* __restrict__ b_out,
    double* __restrict__ part, int use_atomic)
{
    __shared__ float sWin[SWIN_SZ];
    __shared__ float sbin[SBIN_SZ];
    __shared__ float sWh[SWH_SZ];
    __shared__ float sbh[SBH_SZ];
    __shared__ float sWo[SWO_SZ];
    __shared__ float sbo[2];
    __shared__ double sRed[WPB_F][6];

    const int tid = threadIdx.x;
    for (int i = tid; i < 3*HID; i += BLOCK_F) sWin[i] = W_in[i];
    for (int i = 3*HID + tid; i < SWIN_SZ; i += BLOCK_F) sWin[i] = 0.f;
    for (int i = tid; i < HID; i += BLOCK_F) sbin[i] = b_in[i];
    for (int i = HID + tid; i < SBIN_SZ; i += BLOCK_F) sbin[i] = 0.f;
    for (int i = tid; i < NLAYERS*HID*HID; i += BLOCK_F) sWh[i] = W_hid[i];
    for (int i = NLAYERS*HID*HID + tid; i < SWH_SZ; i += BLOCK_F) sWh[i] = 0.f;
    for (int i = tid; i < NLAYERS*HID; i += BLOCK_F) sbh[i] = b_hid[i];
    for (int i = NLAYERS*HID + tid; i < SBH_SZ; i += BLOCK_F) sbh[i] = 0.f;
    for (int i = tid; i < 2*HID; i += BLOCK_F) sWo[i] = W_out[i];
    for (int i = 2*HID + tid; i < SWO_SZ; i += BLOCK_F) sWo[i] = 0.f;
    if (tid < 2) sbo[tid] = b_out[tid];
    __syncthreads();

    const int lane = tid & 63;
    const int wave = tid >> 6;
    const int p    = blockIdx.x * WPB_F + wave;

    const float x0 = x[3*p+0], x1 = x[3*p+1], x2 = x[3*p+2];
    const float w0 = sWin[lane];
    const float w1 = sWin[HID + lane];
    const float w2 = sWin[2*HID + lane];
    float z = fmaf(x0, w0, fmaf(x1, w1, fmaf(x2, w2, sbin[lane])));
    float h = fast_tanh(z);
    float s = 1.f - h*h;
    float hx = s*w0, hy = s*w1, ht = s*w2;
    float hxx = -2.f*h*s*w0*w0;
    float hyy = -2.f*h*s*w1*w1;

    for (int l = 0; l < NLAYERS; ++l) {
        const float* __restrict__ Wl = &sWh[l*HID*HID];
        float za  = sbh[l*HID + lane];
        float zx = 0.f, zy = 0.f, zt = 0.f, zxx = 0.f, zyy = 0.f;
        #pragma unroll
        for (int k = 0; k < HID; ++k) {
            const float w = Wl[k*HID + lane];
            za  = fmaf(readlane_f(h,   k), w, za);
            zx  = fmaf(readlane_f(hx,  k), w, zx);
            zy  = fmaf(readlane_f(hy,  k), w, zy);
            zt  = fmaf(readlane_f(ht,  k), w, zt);
            zxx = fmaf(readlane_f(hxx, k), w, zxx);
            zyy = fmaf(readlane_f(hyy, k), w, zyy);
        }
        const float hn = fast_tanh(za);
        const float sn = 1.f - hn*hn;
        hxx = fmaf(sn, zxx, -2.f*hn*sn*zx*zx);
        hyy = fmaf(sn, zyy, -2.f*hn*sn*zy*zy);
        hx = sn*zx; hy = sn*zy; ht = sn*zt;
        h = hn;
    }

    const float wo0 = sWo[lane*2+0];
    const float wo1 = sWo[lane*2+1];
    const bool act = (lane < HID);
    float pu   = act ? h  *wo0 : 0.f;
    float pv   = act ? h  *wo1 : 0.f;
    float put  = act ? ht *wo0 : 0.f;
    float pvt  = act ? ht *wo1 : 0.f;
    float puxx = act ? hxx*wo0 : 0.f;
    float pvxx = act ? hxx*wo1 : 0.f;
    float puyy = act ? hyy*wo0 : 0.f;
    float pvyy = act ? hyy*wo1 : 0.f;
    #pragma unroll
    for (int off = 32; off > 0; off >>= 1) {
        pu   += __shfl_xor(pu,   off);
        pv   += __shfl_xor(pv,   off);
        put  += __shfl_xor(put,  off);
        pvt  += __shfl_xor(pvt,  off);
        puxx += __shfl_xor(puxx, off);
        pvxx += __shfl_xor(pvxx, off);
        puyy += __shfl_xor(puyy, off);
        pvyy += __shfl_xor(pvyy, off);
    }
    const float u = pu + sbo[0];
    const float v = pv + sbo[1];
    const float Q = u*u + v*v;
    const float g1 = pvt - 0.5f*puxx - 0.5f*pvyy - Q*u + v;
    const float g2 = put + 0.5f*pvxx - 0.5f*puyy + Q*v + u;
    const float h1 = 0.5f*puyy, h2 = 0.5f*pvyy;
    const float k1 = Q*v,       k2 = Q*u;

    const double a0 = (double)g1*(double)g1 + (double)g2*(double)g2;
    const double a1 = (double)h1*(double)h1 + (double)h2*(double)h2;
    const double a2 = (double)k1*(double)k1 + (double)k2*(double)k2;
    const double a3 = (double)g2*(double)h2 - (double)g1*(double)h1;
    const double a4 = (double)g1*(double)k1 + (double)g2*(double)k2;
    const double a5 = (double)h1*(double)k1 - (double)h2*(double)k2;

    if (lane == 0) {
        sRed[wave][0] = a0; sRed[wave][1] = a1; sRed[wave][2] = a2;
        sRed[wave][3] = a3; sRed[wave][4] = a4; sRed[wave][5] = a5;
    }
    __syncthreads();
    if (tid < 6) {
        double t = 0.0;
        #pragma unroll
        for (int wv = 0; wv < WPB_F; ++wv) t += sRed[wv][tid];
        if (use_atomic) atomicAdd(&part[tid], t);
        else            part[blockIdx.x * 6 + tid] = t;
    }
}

// =================== para: reduce partials + 5000 outputs ===================
__global__ __launch_bounds__(512) void para_kernel(
    const float* __restrict__ para,
    const double* __restrict__ part, int nsets,
    float* __restrict__ out)
{
    __shared__ double sW[8][6];
    __shared__ double sS[6];
    const int tid  = threadIdx.x;
    const int lane = tid & 63;
    const int wave = tid >> 6;

    double c0=0,c1=0,c2=0,c3=0,c4=0,c5=0;
    for (int i = tid; i < nsets; i += 512) {
        const double* qp = &part[i*6];
        c0 += qp[0]; c1 += qp[1]; c2 += qp[2]; c3 += qp[3]; c4 += qp[4]; c5 += qp[5];
    }
    #pragma unroll
    for (int off = 32; off > 0; off >>= 1) {
        c0 += __shfl_xor(c0, off); c1 += __shfl_xor(c1, off);
        c2 += __shfl_xor(c2, off); c3 += __shfl_xor(c3, off);
        c4 += __shfl_xor(c4, off); c5 += __shfl_xor(c5, off);
    }
    if (lane == 0) {
        sW[wave][0]=c0; sW[wave][1]=c1; sW[wave][2]=c2;
        sW[wave][3]=c3; sW[wave][4]=c4; sW[wave][5]=c5;
    }
    __syncthreads();
    if (tid < 6) {
        double t = 0.0;
        #pragma unroll
        for (int wv = 0; wv < 8; ++wv) t += sW[wv][tid];
        sS[tid] = t;
    }
    __syncthreads();

    const double S0=sS[0], S1=sS[1], S2=sS[2], S3=sS[3], S4=sS[4], S5=sS[5];
    for (int p = blockIdx.x * 512 + tid; p < NPARA; p += gridDim.x * 512) {
        const double a  = (double)para[3*p+0];
        const double cc = (double)para[3*p+2];
        const double r = S0 + a*a*S1 + cc*cc*S2 + 2.0*a*S3 - 2.0*cc*S4 + 2.0*a*cc*S5;
        out[p] = (float)(r * (1.0 / (double)NPTS));
    }
}

extern "C" void kernel_launch(void* const* d_in, const int* in_sizes, int n_in,
                              void* d_out, int out_size, void* d_ws, size_t ws_size,
                              hipStream_t stream) {
    const float* x     = (const float*)d_in[0];
    const float* para  = (const float*)d_in[1];
    const float* W_in  = (const float*)d_in[2];
    const float* b_in  = (const float*)d_in[3];
    const float* W_hid = (const float*)d_in[4];
    const float* b_hid = (const float*)d_in[5];
    const float* W_out = (const float*)d_in[6];
    const float* b_out = (const float*)d_in[7];

    char*   wsbase = (char*)d_ws;
    double* part   = (double*)d_ws;

    if (ws_size >= (size_t)WS_NEED) {
        prep_kernel<<<11, 256, 0, stream>>>(W_in, b_in, W_hid, b_hid, W_out, wsbase);
        point_mfma_kernel<<<NBLK, 512, 0, stream>>>(x, b_out, wsbase, part);
        para_kernel<<<10, 512, 0, stream>>>(para, part, NBLK*2, (float*)d_out);
    } else if (ws_size >= (size_t)(GRID_F * 6 * sizeof(double))) {
        point_fallback_kernel<<<GRID_F, BLOCK_F, 0, stream>>>(
            x, W_in, b_in, W_hid, b_hid, W_out, b_out, part, 0);
        para_kernel<<<10, 512, 0, stream>>>(para, part, GRID_F, (float*)d_out);
    } else {
        hipMemsetAsync(part, 0, 6*sizeof(double), stream);
        point_fallback_kernel<<<GRID_F, BLOCK_F, 0, stream>>>(
            x, W_in, b_in, W_hid, b_hid, W_out, b_out, part, 1);
        para_kernel<<<10, 512, 0, stream>>>(para, part, 1, (float*)d_out);
    }
}

// Round 11
// 88.226 us; speedup vs baseline: 1.0065x; 1.0065x over previous
//
#include <hip/hip_runtime.h>
#include <math.h>

#define HID 50
#define NPTS 8192
#define NPARA 5000
#define NLAYERS 4
#define NBLK 512           // 16 points per block

typedef float f32x4 __attribute__((ext_vector_type(4)));
typedef short short8 __attribute__((ext_vector_type(8)));

union U4S8 { uint4 u; short8 s; };

// ---- workspace layout (bytes) ----
#define WS_PART 0          // 512 blocks * 6 doubles = 24576
#define WS_FRAG 32768      // 32 frag-units * 2(hi/lo) * 64 lanes * 16B = 65536
#define WS_WIN  98304      // W_in padded 3*64 f32
#define WS_BIN  99072      // b_in padded 64 f32
#define WS_BH   99328      // b_hid padded 4*64 f32
#define WS_WOUT 100352     // W_out padded 64*2 f32
#define WS_NEED 100864

// packed state: S[comp][k][p] as u32 (bf16 hi | lo<<16), k-stride 21 words.
// Ping-pong double buffer: layer l reads buf[l&1], writes buf[1-(l&1)] ->
// no WAR hazard inside a layer -> ONE barrier per layer instead of two.
#define S_STRIDE 21
#define S_COMP   (64*S_STRIDE)      // 1344 u32 per component
#define S_WORDS  (6*S_COMP)         // 8064 u32 = 32256 B per buffer

#define SEL_HI 0x05040100u
#define SEL_LO 0x07060302u

__device__ __forceinline__ float fast_tanh(float x) {
    const float ax = __builtin_fabsf(x);
    const float e  = __expf(2.0f * ax);
    const float r  = __builtin_amdgcn_rcpf(e + 1.0f);
    const float t  = fmaf(-2.0f, r, 1.0f);
    return __builtin_copysignf(t, x);
}

// split fp32 ~= hi + lo (bf16 each), |err| ~ 2^-17 |x|
__device__ __forceinline__ void split_bf16(float x, unsigned &hi, unsigned &lo) {
    const unsigned u = __float_as_uint(x);
    const unsigned h = u & 0xFFFF0000u;
    const float rem  = x - __uint_as_float(h);
    const unsigned r = __float_as_uint(rem);
    hi = h >> 16;
    lo = (r + 0x7FFFu + ((r >> 16) & 1u)) >> 16;
}

__device__ __forceinline__ unsigned pack_split(float x) {
    unsigned hi, lo;
    split_bf16(x, hi, lo);
    return hi | (lo << 16);
}

__device__ __forceinline__ float unpack_sum(unsigned w) {
    return __uint_as_float(w << 16) + __uint_as_float(w & 0xFFFF0000u);
}

__device__ __forceinline__ uint4 pack8(const unsigned v[8]) {
    return make_uint4(v[0] | (v[1] << 16), v[2] | (v[3] << 16),
                      v[4] | (v[5] << 16), v[6] | (v[7] << 16));
}

// ---- prep: split weights into bf16 hi/lo B-fragments + pad arrays ----
// B-frag for (l,c,t): lane(q=lane>>4, n=lane&15) holds B[k=c*32+q*8+jj][t*16+n]
__global__ __launch_bounds__(256) void prep_kernel(
    const float* __restrict__ W_in, const float* __restrict__ b_in,
    const float* __restrict__ W_hid, const float* __restrict__ b_hid,
    const float* __restrict__ W_out, char* __restrict__ wsbase)
{
    const int gid = blockIdx.x * 256 + threadIdx.x;
    if (gid < 2048) {
        const int fid = gid >> 6, lane = gid & 63;
        const int l = fid >> 3, c = (fid >> 2) & 1, t = fid & 3;
        const int q = lane >> 4, n = lane & 15;
        const int gn = t*16 + n;
        unsigned hi[8], lo[8];
        #pragma unroll
        for (int jj = 0; jj < 8; ++jj) {
            const int k = c*32 + q*8 + jj;
            const float w = (k < HID && gn < HID) ? W_hid[(l*HID + k)*HID + gn] : 0.f;
            split_bf16(w, hi[jj], lo[jj]);
        }
        uint4* frag = (uint4*)(wsbase + WS_FRAG);
        frag[(fid*2 + 0)*64 + lane] = pack8(hi);
        frag[(fid*2 + 1)*64 + lane] = pack8(lo);
    } else if (gid < 2240) {
        const int i = gid - 2048, d = i >> 6, j = i & 63;
        ((float*)(wsbase + WS_WIN))[i] = (j < HID) ? W_in[d*HID + j] : 0.f;
    } else if (gid < 2304) {
        const int j = gid - 2240;
        ((float*)(wsbase + WS_BIN))[j] = (j < HID) ? b_in[j] : 0.f;
    } else if (gid < 2560) {
        const int i = gid - 2304, l = i >> 6, j = i & 63;
        ((float*)(wsbase + WS_BH))[i] = (j < HID) ? b_hid[l*HID + j] : 0.f;
    } else if (gid < 2688) {
        const int i = gid - 2560, j = i >> 1, s = i & 1;
        ((float*)(wsbase + WS_WOUT))[i] = (j < HID) ? W_out[j*2 + s] : 0.f;
    }
}

// ---- main: 4 waves/block, 16 points/block; wave w owns j-tile w; ping-pong S ----
__global__ __launch_bounds__(256, 2) void point_mfma_kernel(
    const float* __restrict__ x,
    const float* __restrict__ b_out,
    const char* __restrict__ wsbase,
    double* __restrict__ part)
{
    __shared__ unsigned S[2 * S_WORDS];

    const int tid  = threadIdx.x;
    const int wave = tid >> 6;
    const int lane = tid & 63;
    const int q = lane >> 4, L = lane & 15;

    const float* Winp = (const float*)(wsbase + WS_WIN);
    const float* binp = (const float*)(wsbase + WS_BIN);
    const float* bhp  = (const float*)(wsbase + WS_BH);
    const float* wop  = (const float*)(wsbase + WS_WOUT);
    const uint4* frag = (const uint4*)(wsbase + WS_FRAG);

    // ---- input layer: lane (q,L) seeds j = 16w+4q+jj (jj<4) for point p=L ----
    // writes buf0
    const int pid = blockIdx.x * 16 + L;
    const float x0 = x[3*pid+0], x1 = x[3*pid+1], x2 = x[3*pid+2];
    #pragma unroll
    for (int jj = 0; jj < 4; ++jj) {
        const int j = 16*wave + 4*q + jj;
        const float w0 = Winp[j], w1 = Winp[64 + j], w2 = Winp[128 + j];
        const float z  = fmaf(x0, w0, fmaf(x1, w1, fmaf(x2, w2, binp[j])));
        const float h  = fast_tanh(z);
        const float s  = 1.f - h*h;
        const float g  = -2.f*h*s;
        const int base = j*S_STRIDE + L;
        S[0*S_COMP + base] = pack_split(h);
        S[1*S_COMP + base] = pack_split(s*w0);
        S[2*S_COMP + base] = pack_split(s*w1);
        S[3*S_COMP + base] = pack_split(s*w2);
        S[4*S_COMP + base] = pack_split(g*w0*w0);
        S[5*S_COMP + base] = pack_split(g*w1*w1);
    }
    __syncthreads();

    // ---- hidden layers: read buf[l&1], write buf[1-(l&1)]; 1 barrier/layer ----
    #pragma unroll 1
    for (int l = 0; l < NLAYERS; ++l) {
        unsigned* __restrict__ Ssrc = &S[(l & 1) * S_WORDS];
        unsigned* __restrict__ Sdst = &S[(1 - (l & 1)) * S_WORDS];

        f32x4 acc[6];
        #pragma unroll
        for (int comp = 0; comp < 6; ++comp) acc[comp] = (f32x4){0.f,0.f,0.f,0.f};

        #pragma unroll
        for (int c = 0; c < 2; ++c) {
            U4S8 bh, bl;
            {
                const int fi = (l*2 + c)*4 + wave;
                bh.u = frag[(fi*2 + 0)*64 + lane];
                bl.u = frag[(fi*2 + 1)*64 + lane];
            }
            #pragma unroll
            for (int comp = 0; comp < 6; ++comp) {
                const int base = comp*S_COMP + (c*32 + q*8)*S_STRIDE + L;
                unsigned w[8];
                #pragma unroll
                for (int jj = 0; jj < 8; ++jj) w[jj] = Ssrc[base + jj*S_STRIDE];
                U4S8 ah, al;
                ah.u = make_uint4(
                    __builtin_amdgcn_perm(w[1], w[0], SEL_HI),
                    __builtin_amdgcn_perm(w[3], w[2], SEL_HI),
                    __builtin_amdgcn_perm(w[5], w[4], SEL_HI),
                    __builtin_amdgcn_perm(w[7], w[6], SEL_HI));
                al.u = make_uint4(
                    __builtin_amdgcn_perm(w[1], w[0], SEL_LO),
                    __builtin_amdgcn_perm(w[3], w[2], SEL_LO),
                    __builtin_amdgcn_perm(w[5], w[4], SEL_LO),
                    __builtin_amdgcn_perm(w[7], w[6], SEL_LO));
                acc[comp] = __builtin_amdgcn_mfma_f32_16x16x32_bf16(ah.s, bh.s, acc[comp], 0, 0, 0);
                acc[comp] = __builtin_amdgcn_mfma_f32_16x16x32_bf16(ah.s, bl.s, acc[comp], 0, 0, 0);
                acc[comp] = __builtin_amdgcn_mfma_f32_16x16x32_bf16(al.s, bh.s, acc[comp], 0, 0, 0);
            }
        }
        // no barrier here: epilogue writes the OTHER buffer (no WAR hazard)

        // epilogue: C/D col(j)=lane&15, row(p)=q*4+r -> write Sdst[comp][j][p]
        {
            const int j = wave*16 + L;
            const float bias = bhp[l*64 + j];
            #pragma unroll
            for (int r = 0; r < 4; ++r) {
                const int p = 4*q + r;
                const float za  = acc[0][r] + bias;
                const float zx  = acc[1][r];
                const float zy  = acc[2][r];
                const float zt  = acc[3][r];
                const float zxx = acc[4][r];
                const float zyy = acc[5][r];
                const float h = fast_tanh(za);
                const float s = 1.f - h*h;
                const float g = -2.f*h*s;
                const int base = j*S_STRIDE + p;
                Sdst[0*S_COMP + base] = pack_split(h);
                Sdst[1*S_COMP + base] = pack_split(s*zx);
                Sdst[2*S_COMP + base] = pack_split(s*zy);
                Sdst[3*S_COMP + base] = pack_split(s*zt);
                Sdst[4*S_COMP + base] = pack_split(fmaf(g*zx, zx, s*zxx));
                Sdst[5*S_COMP + base] = pack_split(fmaf(g*zy, zy, s*zyy));
            }
        }
        __syncthreads();   // writes visible before next layer's reads
    }

    // ---- output layer: final state is in buf0 (NLAYERS even) ----
    float du=0.f, dv=0.f, dut=0.f, dvt=0.f, duxx=0.f, dvxx=0.f, duyy=0.f, dvyy=0.f;
    #pragma unroll
    for (int jj = 0; jj < 4; ++jj) {
        const int j = 16*wave + 4*q + jj;
        const int base = j*S_STRIDE + L;
        const float sh  = unpack_sum(S[0*S_COMP + base]);
        const float st_ = unpack_sum(S[3*S_COMP + base]);
        const float sxx = unpack_sum(S[4*S_COMP + base]);
        const float syy = unpack_sum(S[5*S_COMP + base]);
        const float w0 = wop[j*2 + 0], w1 = wop[j*2 + 1];
        du   = fmaf(sh,  w0, du);   dv   = fmaf(sh,  w1, dv);
        dut  = fmaf(st_, w0, dut);  dvt  = fmaf(st_, w1, dvt);
        duxx = fmaf(sxx, w0, duxx); dvxx = fmaf(sxx, w1, dvxx);
        duyy = fmaf(syy, w0, duyy); dvyy = fmaf(syy, w1, dvyy);
    }
    #pragma unroll
    for (int off = 16; off <= 32; off <<= 1) {   // reduce over q
        du   += __shfl_xor(du,   off); dv   += __shfl_xor(dv,   off);
        dut  += __shfl_xor(dut,  off); dvt  += __shfl_xor(dvt,  off);
        duxx += __shfl_xor(duxx, off); dvxx += __shfl_xor(dvxx, off);
        duyy += __shfl_xor(duyy, off); dvyy += __shfl_xor(dvyy, off);
    }
    // xd overlay on dead buf1 (last written by layer 2, last read by layer 3)
    float* __restrict__ xd = (float*)&S[S_WORDS];
    if (wave >= 1 && lane < 16) {
        float* d = &xd[((wave-1)*16 + lane) * 8];
        d[0]=du; d[1]=dv; d[2]=dut; d[3]=dvt;
        d[4]=duxx; d[5]=dvxx; d[6]=duyy; d[7]=dvyy;
    }
    __syncthreads();
    if (wave == 0) {
        #pragma unroll
        for (int wv = 0; wv < 3; ++wv) {
            const float* d = &xd[(wv*16 + L) * 8];
            du += d[0]; dv += d[1]; dut += d[2]; dvt += d[3];
            duxx += d[4]; dvxx += d[5]; duyy += d[6]; dvyy += d[7];
        }
        const float u = du + b_out[0];
        const float v = dv + b_out[1];
        const float Q = u*u + v*v;
        const float g1 = dvt - 0.5f*duxx - 0.5f*dvyy - Q*u + v;   // base1
        const float g2 = dut + 0.5f*dvxx - 0.5f*duyy + Q*v + u;   // base2
        const float h1 = 0.5f*duyy, h2 = 0.5f*dvyy;
        const float k1 = Q*v,       k2 = Q*u;

        const double m = (lane < 16) ? 1.0 : 0.0;   // one contribution per point
        double a0 = m * ((double)g1*(double)g1 + (double)g2*(double)g2);
        double a1 = m * ((double)h1*(double)h1 + (double)h2*(double)h2);
        double a2 = m * ((double)k1*(double)k1 + (double)k2*(double)k2);
        double a3 = m * ((double)g2*(double)h2 - (double)g1*(double)h1);
        double a4 = m * ((double)g1*(double)k1 + (double)g2*(double)k2);
        double a5 = m * ((double)h1*(double)k1 - (double)h2*(double)k2);
        #pragma unroll
        for (int off = 1; off <= 32; off <<= 1) {
            a0 += __shfl_xor(a0, off); a1 += __shfl_xor(a1, off);
            a2 += __shfl_xor(a2, off); a3 += __shfl_xor(a3, off);
            a4 += __shfl_xor(a4, off); a5 += __shfl_xor(a5, off);
        }
        if (lane == 0) {
            double* o = &part[blockIdx.x * 6];
            o[0] = a0; o[1] = a1; o[2] = a2; o[3] = a3; o[4] = a4; o[5] = a5;
        }
    }
}

// =================== fallback (proven R4 readlane kernel) ===================
#define BLOCK_F 1024
#define WPB_F   16
#define GRID_F  512
#define SWIN_SZ (3*HID + 16)
#define SBIN_SZ (HID + 16)
#define SWH_SZ  (NLAYERS*HID*HID + 16)
#define SBH_SZ  (NLAYERS*HID + 16)
#define SWO_SZ  (2*64)

__device__ __forceinline__ float readlane_f(float v, int k) {
    return __int_as_float(__builtin_amdgcn_readlane(__float_as_int(v), k));
}

__global__ __launch_bounds__(BLOCK_F, 8) void point_fallback_kernel(
    const float* __restrict__ x,
    const float* __restrict__ W_in, const float* __restrict__ b_in,
    const float* __restrict__ W_hid, const float* __restrict__ b_hid,
    const float* __restrict__ W_out, const float* __restrict__ b_out,
    double* __restrict__ part, int use_atomic)
{
    __shared__ float sWin[SWIN_SZ];
    __shared__ float sbin[SBIN_SZ];
    __shared__ float sWh[SWH_SZ];
    __shared__ float sbh[SBH_SZ];
    __shared__ float sWo[SWO_SZ];
    __shared__ float sbo[2];
    __shared__ double sRed[WPB_F][6];

    const int tid = threadIdx.x;
    for (int i = tid; i < 3*HID; i += BLOCK_F) sWin[i] = W_in[i];
    for (int i = 3*HID + tid; i < SWIN_SZ; i += BLOCK_F) sWin[i] = 0.f;
    for (int i = tid; i < HID; i += BLOCK_F) sbin[i] = b_in[i];
    for (int i = HID + tid; i < SBIN_SZ; i += BLOCK_F) sbin[i] = 0.f;
    for (int i = tid; i < NLAYERS*HID*HID; i += BLOCK_F) sWh[i] = W_hid[i];
    for (int i = NLAYERS*HID*HID + tid; i < SWH_SZ; i += BLOCK_F) sWh[i] = 0.f;
    for (int i = tid; i < NLAYERS*HID; i += BLOCK_F) sbh[i] = b_hid[i];
    for (int i = NLAYERS*HID + tid; i < SBH_SZ; i += BLOCK_F) sbh[i] = 0.f;
    for (int i = tid; i < 2*HID; i += BLOCK_F) sWo[i] = W_out[i];
    for (int i = 2*HID + tid; i < SWO_SZ; i += BLOCK_F) sWo[i] = 0.f;
    if (tid < 2) sbo[tid] = b_out[tid];
    __syncthreads();

    const int lane = tid & 63;
    const int wave = tid >> 6;
    const int p    = blockIdx.x * WPB_F + wave;

    const float x0 = x[3*p+0], x1 = x[3*p+1], x2 = x[3*p+2];
    const float w0 = sWin[lane];
    const float w1 = sWin[HID + lane];
    const float w2 = sWin[2*HID + lane];
    float z = fmaf(x0, w0, fmaf(x1, w1, fmaf(x2, w2, sbin[lane])));
    float h = fast_tanh(z);
    float s = 1.f - h*h;
    float hx = s*w0, hy = s*w1, ht = s*w2;
    float hxx = -2.f*h*s*w0*w0;
    float hyy = -2.f*h*s*w1*w1;

    for (int l = 0; l < NLAYERS; ++l) {
        const float* __restrict__ Wl = &sWh[l*HID*HID];
        float za  = sbh[l*HID + lane];
        float zx = 0.f, zy = 0.f, zt = 0.f, zxx = 0.f, zyy = 0.f;
        #pragma unroll
        for (int k = 0; k < HID; ++k) {
            const float w = Wl[k*HID + lane];
            za  = fmaf(readlane_f(h,   k), w, za);
            zx  = fmaf(readlane_f(hx,  k), w, zx);
            zy  = fmaf(readlane_f(hy,  k), w, zy);
            zt  = fmaf(readlane_f(ht,  k), w, zt);
            zxx = fmaf(readlane_f(hxx, k), w, zxx);
            zyy = fmaf(readlane_f(hyy, k), w, zyy);
        }
        const float hn = fast_tanh(za);
        const float sn = 1.f - hn*hn;
        hxx = fmaf(sn, zxx, -2.f*hn*sn*zx*zx);
        hyy = fmaf(sn, zyy, -2.f*hn*sn*zy*zy);
        hx = sn*zx; hy = sn*zy; ht = sn*zt;
        h = hn;
    }

    const float wo0 = sWo[lane*2+0];
    const float wo1 = sWo[lane*2+1];
    const bool act = (lane < HID);
    float pu   = act ? h  *wo0 : 0.f;
    float pv   = act ? h  *wo1 : 0.f;
    float put  = act ? ht *wo0 : 0.f;
    float pvt  = act ? ht *wo1 : 0.f;
    float puxx = act ? hxx*wo0 : 0.f;
    float pvxx = act ? hxx*wo1 : 0.f;
    float puyy = act ? hyy*wo0 : 0.f;
    float pvyy = act ? hyy*wo1 : 0.f;
    #pragma unroll
    for (int off = 32; off > 0; off >>= 1) {
        pu   += __shfl_xor(pu,   off);
        pv   += __shfl_xor(pv,   off);
        put  += __shfl_xor(put,  off);
        pvt  += __shfl_xor(pvt,  off);
        puxx += __shfl_xor(puxx, off);
        pvxx += __shfl_xor(pvxx, off);
        puyy += __shfl_xor(puyy, off);
        pvyy += __shfl_xor(pvyy, off);
    }
    const float u = pu + sbo[0];
    const float v = pv + sbo[1];
    const float Q = u*u + v*v;
    const float g1 = pvt - 0.5f*puxx - 0.5f*pvyy - Q*u + v;
    const float g2 = put + 0.5f*pvxx - 0.5f*puyy + Q*v + u;
    const float h1 = 0.5f*puyy, h2 = 0.5f*pvyy;
    const float k1 = Q*v,       k2 = Q*u;

    const double a0 = (double)g1*(double)g1 + (double)g2*(double)g2;
    const double a1 = (double)h1*(double)h1 + (double)h2*(double)h2;
    const double a2 = (double)k1*(double)k1 + (double)k2*(double)k2;
    const double a3 = (double)g2*(double)h2 - (double)g1*(double)h1;
    const double a4 = (double)g1*(double)k1 + (double)g2*(double)k2;
    const double a5 = (double)h1*(double)k1 - (double)h2*(double)k2;

    if (lane == 0) {
        sRed[wave][0] = a0; sRed[wave][1] = a1; sRed[wave][2] = a2;
        sRed[wave][3] = a3; sRed[wave][4] = a4; sRed[wave][5] = a5;
    }
    __syncthreads();
    if (tid < 6) {
        double t = 0.0;
        #pragma unroll
        for (int wv = 0; wv < WPB_F; ++wv) t += sRed[wv][tid];
        if (use_atomic) atomicAdd(&part[tid], t);
        else            part[blockIdx.x * 6 + tid] = t;
    }
}

// =================== para: reduce partials + 5000 outputs ===================
__global__ __launch_bounds__(512) void para_kernel(
    const float* __restrict__ para,
    const double* __restrict__ part, int nsets,
    float* __restrict__ out)
{
    __shared__ double sW[8][6];
    __shared__ double sS[6];
    const int tid  = threadIdx.x;
    const int lane = tid & 63;
    const int wave = tid >> 6;

    double c0=0,c1=0,c2=0,c3=0,c4=0,c5=0;
    for (int i = tid; i < nsets; i += 512) {
        const double* qp = &part[i*6];
        c0 += qp[0]; c1 += qp[1]; c2 += qp[2]; c3 += qp[3]; c4 += qp[4]; c5 += qp[5];
    }
    #pragma unroll
    for (int off = 32; off > 0; off >>= 1) {
        c0 += __shfl_xor(c0, off); c1 += __shfl_xor(c1, off);
        c2 += __shfl_xor(c2, off); c3 += __shfl_xor(c3, off);
        c4 += __shfl_xor(c4, off); c5 += __shfl_xor(c5, off);
    }
    if (lane == 0) {
        sW[wave][0]=c0; sW[wave][1]=c1; sW[wave][2]=c2;
        sW[wave][3]=c3; sW[wave][4]=c4; sW[wave][5]=c5;
    }
    __syncthreads();
    if (tid < 6) {
        double t = 0.0;
        #pragma unroll
        for (int wv = 0; wv < 8; ++wv) t += sW[wv][tid];
        sS[tid] = t;
    }
    __syncthreads();

    const double S0=sS[0], S1=sS[1], S2=sS[2], S3=sS[3], S4=sS[4], S5=sS[5];
    for (int p = blockIdx.x * 512 + tid; p < NPARA; p += gridDim.x * 512) {
        const double a  = (double)para[3*p+0];
        const double cc = (double)para[3*p+2];
        const double r = S0 + a*a*S1 + cc*cc*S2 + 2.0*a*S3 - 2.0*cc*S4 + 2.0*a*cc*S5;
        out[p] = (float)(r * (1.0 / (double)NPTS));
    }
}

extern "C" void kernel_launch(void* const* d_in, const int* in_sizes, int n_in,
                              void* d_out, int out_size, void* d_ws, size_t ws_size,
                              hipStream_t stream) {
    const float* x     = (const float*)d_in[0];
    const float* para  = (const float*)d_in[1];
    const float* W_in  = (const float*)d_in[2];
    const float* b_in  = (const float*)d_in[3];
    const float* W_hid = (const float*)d_in[4];
    const float* b_hid = (const float*)d_in[5];
    const float* W_out = (const float*)d_in[6];
    const float* b_out = (const float*)d_in[7];

    char*   wsbase = (char*)d_ws;
    double* part   = (double*)d_ws;

    if (ws_size >= (size_t)WS_NEED) {
        prep_kernel<<<11, 256, 0, stream>>>(W_in, b_in, W_hid, b_hid, W_out, wsbase);
        point_mfma_kernel<<<NBLK, 256, 0, stream>>>(x, b_out, wsbase, part);
        para_kernel<<<10, 512, 0, stream>>>(para, part, NBLK, (float*)d_out);
    } else if (ws_size >= (size_t)(GRID_F * 6 * sizeof(double))) {
        point_fallback_kernel<<<GRID_F, BLOCK_F, 0, stream>>>(
            x, W_in, b_in, W_hid, b_hid, W_out, b_out, part, 0);
        para_kernel<<<10, 512, 0, stream>>>(para, part, GRID_F, (float*)d_out);
    } else {
        hipMemsetAsync(part, 0, 6*sizeof(double), stream);
        point_fallback_kernel<<<GRID_F, BLOCK_F, 0, stream>>>(
            x, W_in, b_in, W_hid, b_hid, W_out, b_out, part, 1);
        para_kernel<<<10, 512, 0, stream>>>(para, part, 1, (float*)d_out);
    }
}

// Round 12
// 86.183 us; speedup vs baseline: 1.0304x; 1.0237x over previous
//
#include <hip/hip_runtime.h>
#include <math.h>

#define HID 50
#define NPTS 8192
#define NPARA 5000
#define NLAYERS 4
#define NBLK 512           // 16 points per block

typedef float f32x4 __attribute__((ext_vector_type(4)));
typedef short short8 __attribute__((ext_vector_type(8)));

union U4S8 { uint4 u; short8 s; };

// ---- workspace layout (bytes) ----
#define WS_PART 0          // 512 blocks * 6 doubles = 24576
#define WS_FRAG 32768      // 32 frag-units * 2(hi/lo) * 64 lanes * 16B = 65536
#define WS_WIN  98304      // W_in padded 3*64 f32
#define WS_BIN  99072      // b_in padded 64 f32
#define WS_BH   99328      // b_hid padded 4*64 f32
#define WS_WOUT 100352     // W_out padded 64*2 f32
#define WS_NEED 100864

// packed state: S[comp][k][p] as u32 (bf16 hi | lo<<16), k-stride 21 words
// (all read/write patterns <=2-way bank aliasing = free; 0 conflicts measured)
#define S_STRIDE 21
#define S_COMP   (64*S_STRIDE)      // 1344 u32 per component
#define S_WORDS  (6*S_COMP)         // 8064 u32 = 32256 B

#define SEL_HI 0x05040100u
#define SEL_LO 0x07060302u

__device__ __forceinline__ float fast_tanh(float x) {
    const float ax = __builtin_fabsf(x);
    const float e  = __expf(2.0f * ax);
    const float r  = __builtin_amdgcn_rcpf(e + 1.0f);
    const float t  = fmaf(-2.0f, r, 1.0f);
    return __builtin_copysignf(t, x);
}

// split fp32 ~= hi + lo (bf16 each), |err| ~ 2^-17 |x|
__device__ __forceinline__ void split_bf16(float x, unsigned &hi, unsigned &lo) {
    const unsigned u = __float_as_uint(x);
    const unsigned h = u & 0xFFFF0000u;
    const float rem  = x - __uint_as_float(h);
    const unsigned r = __float_as_uint(rem);
    hi = h >> 16;
    lo = (r + 0x7FFFu + ((r >> 16) & 1u)) >> 16;
}

__device__ __forceinline__ unsigned pack_split(float x) {
    unsigned hi, lo;
    split_bf16(x, hi, lo);
    return hi | (lo << 16);
}

__device__ __forceinline__ float unpack_sum(unsigned w) {
    return __uint_as_float(w << 16) + __uint_as_float(w & 0xFFFF0000u);
}

__device__ __forceinline__ uint4 pack8(const unsigned v[8]) {
    return make_uint4(v[0] | (v[1] << 16), v[2] | (v[3] << 16),
                      v[4] | (v[5] << 16), v[6] | (v[7] << 16));
}

// ---- prep: split weights into bf16 hi/lo B-fragments + pad arrays ----
// B-frag for (l,c,t): lane(q=lane>>4, n=lane&15) holds B[k=c*32+q*8+jj][t*16+n]
__global__ __launch_bounds__(256) void prep_kernel(
    const float* __restrict__ W_in, const float* __restrict__ b_in,
    const float* __restrict__ W_hid, const float* __restrict__ b_hid,
    const float* __restrict__ W_out, char* __restrict__ wsbase)
{
    const int gid = blockIdx.x * 256 + threadIdx.x;
    if (gid < 2048) {
        const int fid = gid >> 6, lane = gid & 63;
        const int l = fid >> 3, c = (fid >> 2) & 1, t = fid & 3;
        const int q = lane >> 4, n = lane & 15;
        const int gn = t*16 + n;
        unsigned hi[8], lo[8];
        #pragma unroll
        for (int jj = 0; jj < 8; ++jj) {
            const int k = c*32 + q*8 + jj;
            const float w = (k < HID && gn < HID) ? W_hid[(l*HID + k)*HID + gn] : 0.f;
            split_bf16(w, hi[jj], lo[jj]);
        }
        uint4* frag = (uint4*)(wsbase + WS_FRAG);
        frag[(fid*2 + 0)*64 + lane] = pack8(hi);
        frag[(fid*2 + 1)*64 + lane] = pack8(lo);
    } else if (gid < 2240) {
        const int i = gid - 2048, d = i >> 6, j = i & 63;
        ((float*)(wsbase + WS_WIN))[i] = (j < HID) ? W_in[d*HID + j] : 0.f;
    } else if (gid < 2304) {
        const int j = gid - 2240;
        ((float*)(wsbase + WS_BIN))[j] = (j < HID) ? b_in[j] : 0.f;
    } else if (gid < 2560) {
        const int i = gid - 2304, l = i >> 6, j = i & 63;
        ((float*)(wsbase + WS_BH))[i] = (j < HID) ? b_hid[l*HID + j] : 0.f;
    } else if (gid < 2688) {
        const int i = gid - 2560, j = i >> 1, s = i & 1;
        ((float*)(wsbase + WS_WOUT))[i] = (j < HID) ? W_out[j*2 + s] : 0.f;
    }
}

// ---- main: 4 waves/block, 16 points/block; wave w owns j-tile w (16 j) ----
__global__ __launch_bounds__(256, 2) void point_mfma_kernel(
    const float* __restrict__ x,
    const float* __restrict__ b_out,
    const char* __restrict__ wsbase,
    double* __restrict__ part)
{
    __shared__ unsigned S[S_WORDS];
    __shared__ float xd[3][16][8];

    const int tid  = threadIdx.x;
    const int wave = tid >> 6;
    const int lane = tid & 63;
    const int q = lane >> 4, L = lane & 15;

    const float* Winp = (const float*)(wsbase + WS_WIN);
    const float* binp = (const float*)(wsbase + WS_BIN);
    const float* bhp  = (const float*)(wsbase + WS_BH);
    const float* wop  = (const float*)(wsbase + WS_WOUT);
    const uint4* frag = (const uint4*)(wsbase + WS_FRAG);

    // ---- input layer: lane (q,L) seeds j = 16w+4q+jj (jj<4) for point p=L ----
    const int pid = blockIdx.x * 16 + L;
    const float x0 = x[3*pid+0], x1 = x[3*pid+1], x2 = x[3*pid+2];
    #pragma unroll
    for (int jj = 0; jj < 4; ++jj) {
        const int j = 16*wave + 4*q + jj;
        const float w0 = Winp[j], w1 = Winp[64 + j], w2 = Winp[128 + j];
        const float z  = fmaf(x0, w0, fmaf(x1, w1, fmaf(x2, w2, binp[j])));
        const float h  = fast_tanh(z);
        const float s  = 1.f - h*h;
        const float g  = -2.f*h*s;
        const int base = j*S_STRIDE + L;
        S[0*S_COMP + base] = pack_split(h);
        S[1*S_COMP + base] = pack_split(s*w0);
        S[2*S_COMP + base] = pack_split(s*w1);
        S[3*S_COMP + base] = pack_split(s*w2);
        S[4*S_COMP + base] = pack_split(g*w0*w0);
        S[5*S_COMP + base] = pack_split(g*w1*w1);
    }
    __syncthreads();

    // ---- hidden layers ----
    #pragma unroll 1
    for (int l = 0; l < NLAYERS; ++l) {
        f32x4 acc[6];
        #pragma unroll
        for (int comp = 0; comp < 6; ++comp) acc[comp] = (f32x4){0.f,0.f,0.f,0.f};

        // stage A per c-half to cap live VGPRs; all reads precede the barrier
        #pragma unroll
        for (int c = 0; c < 2; ++c) {
            U4S8 bh, bl;
            {
                const int fi = (l*2 + c)*4 + wave;
                bh.u = frag[(fi*2 + 0)*64 + lane];
                bl.u = frag[(fi*2 + 1)*64 + lane];
            }
            #pragma unroll
            for (int comp = 0; comp < 6; ++comp) {
                const int base = comp*S_COMP + (c*32 + q*8)*S_STRIDE + L;
                unsigned w[8];
                #pragma unroll
                for (int jj = 0; jj < 8; ++jj) w[jj] = S[base + jj*S_STRIDE];
                U4S8 ah, al;
                ah.u = make_uint4(
                    __builtin_amdgcn_perm(w[1], w[0], SEL_HI),
                    __builtin_amdgcn_perm(w[3], w[2], SEL_HI),
                    __builtin_amdgcn_perm(w[5], w[4], SEL_HI),
                    __builtin_amdgcn_perm(w[7], w[6], SEL_HI));
                al.u = make_uint4(
                    __builtin_amdgcn_perm(w[1], w[0], SEL_LO),
                    __builtin_amdgcn_perm(w[3], w[2], SEL_LO),
                    __builtin_amdgcn_perm(w[5], w[4], SEL_LO),
                    __builtin_amdgcn_perm(w[7], w[6], SEL_LO));
                acc[comp] = __builtin_amdgcn_mfma_f32_16x16x32_bf16(ah.s, bh.s, acc[comp], 0, 0, 0);
                acc[comp] = __builtin_amdgcn_mfma_f32_16x16x32_bf16(ah.s, bl.s, acc[comp], 0, 0, 0);
                acc[comp] = __builtin_amdgcn_mfma_f32_16x16x32_bf16(al.s, bh.s, acc[comp], 0, 0, 0);
            }
        }
        __syncthreads();   // all reads drained before epilogue overwrites S

        // epilogue: C/D col(j)=lane&15, row(p)=q*4+r -> write S[comp][j][p]
        {
            const int j = wave*16 + L;
            const float bias = bhp[l*64 + j];
            #pragma unroll
            for (int r = 0; r < 4; ++r) {
                const int p = 4*q + r;
                const float za  = acc[0][r] + bias;
                const float zx  = acc[1][r];
                const float zy  = acc[2][r];
                const float zt  = acc[3][r];
                const float zxx = acc[4][r];
                const float zyy = acc[5][r];
                const float h = fast_tanh(za);
                const float s = 1.f - h*h;
                const float g = -2.f*h*s;
                const int base = j*S_STRIDE + p;
                S[0*S_COMP + base] = pack_split(h);
                S[1*S_COMP + base] = pack_split(s*zx);
                S[2*S_COMP + base] = pack_split(s*zy);
                S[3*S_COMP + base] = pack_split(s*zt);
                S[4*S_COMP + base] = pack_split(fmaf(g*zx, zx, s*zxx));
                S[5*S_COMP + base] = pack_split(fmaf(g*zy, zy, s*zyy));
            }
        }
        __syncthreads();
    }

    // ---- output layer: lane (q,L) sums j = 16w+4q+jj (jj<4) for point L ----
    float du=0.f, dv=0.f, dut=0.f, dvt=0.f, duxx=0.f, dvxx=0.f, duyy=0.f, dvyy=0.f;
    #pragma unroll
    for (int jj = 0; jj < 4; ++jj) {
        const int j = 16*wave + 4*q + jj;
        const int base = j*S_STRIDE + L;
        const float sh  = unpack_sum(S[0*S_COMP + base]);
        const float st_ = unpack_sum(S[3*S_COMP + base]);
        const float sxx = unpack_sum(S[4*S_COMP + base]);
        const float syy = unpack_sum(S[5*S_COMP + base]);
        const float w0 = wop[j*2 + 0], w1 = wop[j*2 + 1];
        du   = fmaf(sh,  w0, du);   dv   = fmaf(sh,  w1, dv);
        dut  = fmaf(st_, w0, dut);  dvt  = fmaf(st_, w1, dvt);
        duxx = fmaf(sxx, w0, duxx); dvxx = fmaf(sxx, w1, dvxx);
        duyy = fmaf(syy, w0, duyy); dvyy = fmaf(syy, w1, dvyy);
    }
    #pragma unroll
    for (int off = 16; off <= 32; off <<= 1) {   // reduce over q
        du   += __shfl_xor(du,   off); dv   += __shfl_xor(dv,   off);
        dut  += __shfl_xor(dut,  off); dvt  += __shfl_xor(dvt,  off);
        duxx += __shfl_xor(duxx, off); dvxx += __shfl_xor(dvxx, off);
        duyy += __shfl_xor(duyy, off); dvyy += __shfl_xor(dvyy, off);
    }
    if (wave >= 1 && lane < 16) {
        float* d = xd[wave-1][lane];
        d[0]=du; d[1]=dv; d[2]=dut; d[3]=dvt;
        d[4]=duxx; d[5]=dvxx; d[6]=duyy; d[7]=dvyy;
    }
    __syncthreads();
    if (wave == 0) {
        #pragma unroll
        for (int wv = 0; wv < 3; ++wv) {
            const float* d = xd[wv][L];
            du += d[0]; dv += d[1]; dut += d[2]; dvt += d[3];
            duxx += d[4]; dvxx += d[5]; duyy += d[6]; dvyy += d[7];
        }
        const float u = du + b_out[0];
        const float v = dv + b_out[1];
        const float Q = u*u + v*v;
        const float g1 = dvt - 0.5f*duxx - 0.5f*dvyy - Q*u + v;   // base1
        const float g2 = dut + 0.5f*dvxx - 0.5f*duyy + Q*v + u;   // base2
        const float h1 = 0.5f*duyy, h2 = 0.5f*dvyy;
        const float k1 = Q*v,       k2 = Q*u;

        const double m = (lane < 16) ? 1.0 : 0.0;   // one contribution per point
        double a0 = m * ((double)g1*(double)g1 + (double)g2*(double)g2);
        double a1 = m * ((double)h1*(double)h1 + (double)h2*(double)h2);
        double a2 = m * ((double)k1*(double)k1 + (double)k2*(double)k2);
        double a3 = m * ((double)g2*(double)h2 - (double)g1*(double)h1);
        double a4 = m * ((double)g1*(double)k1 + (double)g2*(double)k2);
        double a5 = m * ((double)h1*(double)k1 - (double)h2*(double)k2);
        #pragma unroll
        for (int off = 1; off <= 32; off <<= 1) {
            a0 += __shfl_xor(a0, off); a1 += __shfl_xor(a1, off);
            a2 += __shfl_xor(a2, off); a3 += __shfl_xor(a3, off);
            a4 += __shfl_xor(a4, off); a5 += __shfl_xor(a5, off);
        }
        if (lane == 0) {
            double* o = &part[blockIdx.x * 6];
            o[0] = a0; o[1] = a1; o[2] = a2; o[3] = a3; o[4] = a4; o[5] = a5;
        }
    }
}

// =================== fallback (proven R4 readlane kernel) ===================
#define BLOCK_F 1024
#define WPB_F   16
#define GRID_F  512
#define SWIN_SZ (3*HID + 16)
#define SBIN_SZ (HID + 16)
#define SWH_SZ  (NLAYERS*HID*HID + 16)
#define SBH_SZ  (NLAYERS*HID + 16)
#define SWO_SZ  (2*64)

__device__ __forceinline__ float readlane_f(float v, int k) {
    return __int_as_float(__builtin_amdgcn_readlane(__float_as_int(v), k));
}

__global__ __launch_bounds__(BLOCK_F, 8) void point_fallback_kernel(
    const float* __restrict__ x,
    const float* __restrict__ W_in, const float* __restrict__ b_in,
    const float* __restrict__ W_hid, const float* __restrict__ b_hid,
    const float* __restrict__ W_out, const float* __restrict__ b_out,
    double* __restrict__ part, int use_atomic)
{
    __shared__ float sWin[SWIN_SZ];
    __shared__ float sbin[SBIN_SZ];
    __shared__ float sWh[SWH_SZ];
    __shared__ float sbh[SBH_SZ];
    __shared__ float sWo[SWO_SZ];
    __shared__ float sbo[2];
    __shared__ double sRed[WPB_F][6];

    const int tid = threadIdx.x;
    for (int i = tid; i < 3*HID; i += BLOCK_F) sWin[i] = W_in[i];
    for (int i = 3*HID + tid; i < SWIN_SZ; i += BLOCK_F) sWin[i] = 0.f;
    for (int i = tid; i < HID; i += BLOCK_F) sbin[i] = b_in[i];
    for (int i = HID + tid; i < SBIN_SZ; i += BLOCK_F) sbin[i] = 0.f;
    for (int i = tid; i < NLAYERS*HID*HID; i += BLOCK_F) sWh[i] = W_hid[i];
    for (int i = NLAYERS*HID*HID + tid; i < SWH_SZ; i += BLOCK_F) sWh[i] = 0.f;
    for (int i = tid; i < NLAYERS*HID; i += BLOCK_F) sbh[i] = b_hid[i];
    for (int i = NLAYERS*HID + tid; i < SBH_SZ; i += BLOCK_F) sbh[i] = 0.f;
    for (int i = tid; i < 2*HID; i += BLOCK_F) sWo[i] = W_out[i];
    for (int i = 2*HID + tid; i < SWO_SZ; i += BLOCK_F) sWo[i] = 0.f;
    if (tid < 2) sbo[tid] = b_out[tid];
    __syncthreads();

    const int lane = tid & 63;
    const int wave = tid >> 6;
    const int p    = blockIdx.x * WPB_F + wave;

    const float x0 = x[3*p+0], x1 = x[3*p+1], x2 = x[3*p+2];
    const float w0 = sWin[lane];
    const float w1 = sWin[HID + lane];
    const float w2 = sWin[2*HID + lane];
    float z = fmaf(x0, w0, fmaf(x1, w1, fmaf(x2, w2, sbin[lane])));
    float h = fast_tanh(z);
    float s = 1.f - h*h;
    float hx = s*w0, hy = s*w1, ht = s*w2;
    float hxx = -2.f*h*s*w0*w0;
    float hyy = -2.f*h*s*w1*w1;

    for (int l = 0; l < NLAYERS; ++l) {
        const float* __restrict__ Wl = &sWh[l*HID*HID];
        float za  = sbh[l*HID + lane];
        float zx = 0.f, zy = 0.f, zt = 0.f, zxx = 0.f, zyy = 0.f;
        #pragma unroll
        for (int k = 0; k < HID; ++k) {
            const float w = Wl[k*HID + lane];
            za  = fmaf(readlane_f(h,   k), w, za);
            zx  = fmaf(readlane_f(hx,  k), w, zx);
            zy  = fmaf(readlane_f(hy,  k), w, zy);
            zt  = fmaf(readlane_f(ht,  k), w, zt);
            zxx = fmaf(readlane_f(hxx, k), w, zxx);
            zyy = fmaf(readlane_f(hyy, k), w, zyy);
        }
        const float hn = fast_tanh(za);
        const float sn = 1.f - hn*hn;
        hxx = fmaf(sn, zxx, -2.f*hn*sn*zx*zx);
        hyy = fmaf(sn, zyy, -2.f*hn*sn*zy*zy);
        hx = sn*zx; hy = sn*zy; ht = sn*zt;
        h = hn;
    }

    const float wo0 = sWo[lane*2+0];
    const float wo1 = sWo[lane*2+1];
    const bool act = (lane < HID);
    float pu   = act ? h  *wo0 : 0.f;
    float pv   = act ? h  *wo1 : 0.f;
    float put  = act ? ht *wo0 : 0.f;
    float pvt  = act ? ht *wo1 : 0.f;
    float puxx = act ? hxx*wo0 : 0.f;
    float pvxx = act ? hxx*wo1 : 0.f;
    float puyy = act ? hyy*wo0 : 0.f;
    float pvyy = act ? hyy*wo1 : 0.f;
    #pragma unroll
    for (int off = 32; off > 0; off >>= 1) {
        pu   += __shfl_xor(pu,   off);
        pv   += __shfl_xor(pv,   off);
        put  += __shfl_xor(put,  off);
        pvt  += __shfl_xor(pvt,  off);
        puxx += __shfl_xor(puxx, off);
        pvxx += __shfl_xor(pvxx, off);
        puyy += __shfl_xor(puyy, off);
        pvyy += __shfl_xor(pvyy, off);
    }
    const float u = pu + sbo[0];
    const float v = pv + sbo[1];
    const float Q = u*u + v*v;
    const float g1 = pvt - 0.5f*puxx - 0.5f*pvyy - Q*u + v;
    const float g2 = put + 0.5f*pvxx - 0.5f*puyy + Q*v + u;
    const float h1 = 0.5f*puyy, h2 = 0.5f*pvyy;
    const float k1 = Q*v,       k2 = Q*u;

    const double a0 = (double)g1*(double)g1 + (double)g2*(double)g2;
    const double a1 = (double)h1*(double)h1 + (double)h2*(double)h2;
    const double a2 = (double)k1*(double)k1 + (double)k2*(double)k2;
    const double a3 = (double)g2*(double)h2 - (double)g1*(double)h1;
    const double a4 = (double)g1*(double)k1 + (double)g2*(double)k2;
    const double a5 = (double)h1*(double)k1 - (double)h2*(double)k2;

    if (lane == 0) {
        sRed[wave][0] = a0; sRed[wave][1] = a1; sRed[wave][2] = a2;
        sRed[wave][3] = a3; sRed[wave][4] = a4; sRed[wave][5] = a5;
    }
    __syncthreads();
    if (tid < 6) {
        double t = 0.0;
        #pragma unroll
        for (int wv = 0; wv < WPB_F; ++wv) t += sRed[wv][tid];
        if (use_atomic) atomicAdd(&part[tid], t);
        else            part[blockIdx.x * 6 + tid] = t;
    }
}

// =================== para: reduce partials + 5000 outputs ===================
__global__ __launch_bounds__(512) void para_kernel(
    const float* __restrict__ para,
    const double* __restrict__ part, int nsets,
    float* __restrict__ out)
{
    __shared__ double sW[8][6];
    __shared__ double sS[6];
    const int tid  = threadIdx.x;
    const int lane = tid & 63;
    const int wave = tid >> 6;

    double c0=0,c1=0,c2=0,c3=0,c4=0,c5=0;
    for (int i = tid; i < nsets; i += 512) {
        const double* qp = &part[i*6];
        c0 += qp[0]; c1 += qp[1]; c2 += qp[2]; c3 += qp[3]; c4 += qp[4]; c5 += qp[5];
    }
    #pragma unroll
    for (int off = 32; off > 0; off >>= 1) {
        c0 += __shfl_xor(c0, off); c1 += __shfl_xor(c1, off);
        c2 += __shfl_xor(c2, off); c3 += __shfl_xor(c3, off);
        c4 += __shfl_xor(c4, off); c5 += __shfl_xor(c5, off);
    }
    if (lane == 0) {
        sW[wave][0]=c0; sW[wave][1]=c1; sW[wave][2]=c2;
        sW[wave][3]=c3; sW[wave][4]=c4; sW[wave][5]=c5;
    }
    __syncthreads();
    if (tid < 6) {
        double t = 0.0;
        #pragma unroll
        for (int wv = 0; wv < 8; ++wv) t += sW[wv][tid];
        sS[tid] = t;
    }
    __syncthreads();

    const double S0=sS[0], S1=sS[1], S2=sS[2], S3=sS[3], S4=sS[4], S5=sS[5];
    for (int p = blockIdx.x * 512 + tid; p < NPARA; p += gridDim.x * 512) {
        const double a  = (double)para[3*p+0];
        const double cc = (double)para[3*p+2];
        const double r = S0 + a*a*S1 + cc*cc*S2 + 2.0*a*S3 - 2.0*cc*S4 + 2.0*a*cc*S5;
        out[p] = (float)(r * (1.0 / (double)NPTS));
    }
}

extern "C" void kernel_launch(void* const* d_in, const int* in_sizes, int n_in,
                              void* d_out, int out_size, void* d_ws, size_t ws_size,
                              hipStream_t stream) {
    const float* x     = (const float*)d_in[0];
    const float* para  = (const float*)d_in[1];
    const float* W_in  = (const float*)d_in[2];
    const float* b_in  = (const float*)d_in[3];
    const float* W_hid = (const float*)d_in[4];
    const float* b_hid = (const float*)d_in[5];
    const float* W_out = (const float*)d_in[6];
    const float* b_out = (const float*)d_in[7];

    char*   wsbase = (char*)d_ws;
    double* part   = (double*)d_ws;

    if (ws_size >= (size_t)WS_NEED) {
        prep_kernel<<<11, 256, 0, stream>>>(W_in, b_in, W_hid, b_hid, W_out, wsbase);
        point_mfma_kernel<<<NBLK, 256, 0, stream>>>(x, b_out, wsbase, part);
        para_kernel<<<10, 512, 0, stream>>>(para, part, NBLK, (float*)d_out);
    } else if (ws_size >= (size_t)(GRID_F * 6 * sizeof(double))) {
        point_fallback_kernel<<<GRID_F, BLOCK_F, 0, stream>>>(
            x, W_in, b_in, W_hid, b_hid, W_out, b_out, part, 0);
        para_kernel<<<10, 512, 0, stream>>>(para, part, GRID_F, (float*)d_out);
    } else {
        hipMemsetAsync(part, 0, 6*sizeof(double), stream);
        point_fallback_kernel<<<GRID_F, BLOCK_F, 0, stream>>>(
            x, W_in, b_in, W_hid, b_hid, W_out, b_out, part, 1);
        para_kernel<<<10, 512, 0, stream>>>(para, part, 1, (float*)d_out);
    }
}